// Round 1
// baseline (3667.295 us; speedup 1.0000x reference)
//
#include <hip/hip_runtime.h>
#include <hip/hip_bf16.h>

#define B_    1024
#define T_    50
#define RD_   128
#define RH_   256
#define UIN_  96
#define EIN_  384
#define EH_   1536
#define E_    64

typedef __attribute__((ext_vector_type(8))) short bf16x8;
typedef __attribute__((ext_vector_type(4))) float f32x4;

__device__ __forceinline__ short f2bf(float x) {
  unsigned u = __float_as_uint(x);
  unsigned r = (u + 0x7fffu + ((u >> 16) & 1u)) >> 16;
  return (short)(r & 0xffffu);
}

__device__ __forceinline__ f32x4 bcast4(float v) { f32x4 x = {v, v, v, v}; return x; }

__device__ __forceinline__ float sigf(float x) {
  return __builtin_amdgcn_rcpf(1.0f + __expf(-x));
}
__device__ __forceinline__ float tanh_f(float x) {
  float e = __expf(-2.0f * fabsf(x));
  float t = (1.0f - e) * __builtin_amdgcn_rcpf(1.0f + e);
  return x >= 0.0f ? t : -t;
}

// ---------------- prep: cast LSTM weights to bf16, sum biases ----------------
__global__ void prep_cast(const float* __restrict__ wih0, const float* __restrict__ whh0,
                          const float* __restrict__ wih1, const float* __restrict__ whh1,
                          const float* __restrict__ bi0, const float* __restrict__ bh0,
                          const float* __restrict__ bi1, const float* __restrict__ bh1,
                          short* __restrict__ o_ih0, short* __restrict__ o_hh0,
                          short* __restrict__ o_ih1, short* __restrict__ o_hh1,
                          float* __restrict__ ob0, float* __restrict__ ob1) {
  int i = blockIdx.x * blockDim.x + threadIdx.x;
  if (i < 1024 * 128) o_ih0[i] = f2bf(wih0[i]);
  if (i < 1024 * 256) {
    o_hh0[i] = f2bf(whh0[i]);
    o_ih1[i] = f2bf(wih1[i]);
    o_hh1[i] = f2bf(whh1[i]);
  }
  if (i < 1024) { ob0[i] = bi0[i] + bh0[i]; ob1[i] = bi1[i] + bh1[i]; }
}

// ---------------- generic transpose + cast: src[R][C] f32 -> dst[C][R] bf16 ----------------
__global__ void transpose_cast(const float* __restrict__ src, short* __restrict__ dst,
                               int R, int C) {
  __shared__ float tile[32][33];
  size_t boff = (size_t)blockIdx.z * (size_t)R * (size_t)C;
  int tx = threadIdx.x & 31, ty = threadIdx.x >> 5;
  int r0 = blockIdx.x * 32, c0 = blockIdx.y * 32;
#pragma unroll
  for (int q = 0; q < 4; ++q) {
    int r = r0 + ty + q * 8, c = c0 + tx;
    if (r < R && c < C) tile[ty + q * 8][tx] = src[boff + (size_t)r * C + c];
  }
  __syncthreads();
#pragma unroll
  for (int q = 0; q < 4; ++q) {
    int cr = c0 + ty + q * 8, cc = r0 + tx;
    if (cr < C && cc < R) dst[boff + (size_t)cr * R + cc] = f2bf(tile[tx][ty + q * 8]);
  }
}

// ---------------- MFMA helpers ----------------
// A: lane holds A[m=l15][k = quad*8 .. +8]; B^T layout: lane holds W[n=l15][k=quad*8..+8]
// C: col(n) = lane&15, row(m) = quad*4 + reg
template<int KTOT>
__device__ __forceinline__ void gemm_gates(const short* a_lane, const short* w_lane, int ldw,
                                           f32x4 acc[4][2]) {
#pragma unroll
  for (int k = 0; k < KTOT; k += 32) {
    bf16x8 af = *(const bf16x8*)(a_lane + k);
#pragma unroll
    for (int g = 0; g < 4; ++g) {
#pragma unroll
      for (int u = 0; u < 2; ++u) {
        bf16x8 bf = *(const bf16x8*)(w_lane + (g * 256 + u * 16) * ldw + k);
        acc[g][u] = __builtin_amdgcn_mfma_f32_16x16x32_bf16(af, bf, acc[g][u], 0, 0, 0);
      }
    }
  }
}

template<int KTOT, int NT>
__device__ __forceinline__ void gemm_nt(const short* a_lane, const short* w_lane, int ldw,
                                        f32x4* acc) {
#pragma unroll
  for (int k = 0; k < KTOT; k += 32) {
    bf16x8 af = *(const bf16x8*)(a_lane + k);
#pragma unroll
    for (int u = 0; u < NT; ++u) {
      bf16x8 bf = *(const bf16x8*)(w_lane + u * 16 * ldw + k);
      acc[u] = __builtin_amdgcn_mfma_f32_16x16x32_bf16(af, bf, acc[u], 0, 0, 0);
    }
  }
}

// ---------------- fused gather + 2-layer LSTM + r-MLP + u-MLP -> z ----------------
// 64 blocks x 16 batch rows, 512 threads (8 waves). Wave w owns hidden units [32w,32w+32).
__global__ __launch_bounds__(512) void lstm_fused(
    const int* __restrict__ ratings, const int* __restrict__ user_ids,
    const float* __restrict__ user_data, const float* __restrict__ remb,
    const float* __restrict__ uemb,
    const short* __restrict__ Wih0, const short* __restrict__ Whh0,
    const short* __restrict__ Wih1, const short* __restrict__ Whh1,
    const float* __restrict__ b0, const float* __restrict__ b1,
    const short* __restrict__ rW1T, const float* __restrict__ rb1,
    const short* __restrict__ rW2T, const float* __restrict__ rb2,
    const short* __restrict__ uW1T, const float* __restrict__ ub1,
    const short* __restrict__ uW2T, const float* __restrict__ ub2,
    short* __restrict__ z_out) {
  __shared__ __align__(16) short h0_lds[2][16 * 264];  // +8 pad: b128 reads 2-way only
  __shared__ __align__(16) short h1_lds[2][16 * 264];
  __shared__ __align__(16) short seq_lds[16 * 136];
  __shared__ __align__(16) short r1_lds[16 * 520];

  const int tid = threadIdx.x;
  const int w = tid >> 6;
  const int lane = tid & 63;
  const int l15 = lane & 15;
  const int quad = lane >> 4;
  const int row0 = blockIdx.x * 16;

  for (int i = tid; i < 16 * 264; i += 512) {
    h0_lds[0][i] = 0; h0_lds[1][i] = 0; h1_lds[0][i] = 0; h1_lds[1][i] = 0;
  }

  float b0v[4][2], b1v[4][2];
#pragma unroll
  for (int g = 0; g < 4; ++g)
#pragma unroll
    for (int u = 0; u < 2; ++u) {
      int n = g * 256 + w * 32 + u * 16 + l15;
      b0v[g][u] = b0[n];
      b1v[g][u] = b1[n];
    }

  float c0s[2][4] = {{0,0,0,0},{0,0,0,0}};
  float c1s[2][4] = {{0,0,0,0},{0,0,0,0}};

  const short* wih0_l = Wih0 + (w * 32 + l15) * RD_ + quad * 8;
  const short* whh0_l = Whh0 + (w * 32 + l15) * RH_ + quad * 8;
  const short* wih1_l = Wih1 + (w * 32 + l15) * RH_ + quad * 8;
  const short* whh1_l = Whh1 + (w * 32 + l15) * RH_ + quad * 8;

  const int sr = tid >> 5;        // seq row 0..15 (32 threads per row)
  const int sc = (tid & 31) * 4;  // col group of 4

  __syncthreads();

  for (int t = 0; t < T_; ++t) {
    const int p = t & 1;
    // stage seq_t (gather ratings_emb rows, fp32 -> bf16)
    {
      int idx = ratings[(row0 + sr) * T_ + t];
      const float4 v = *(const float4*)(remb + (size_t)idx * RD_ + sc);
      short4 s;
      s.x = f2bf(v.x); s.y = f2bf(v.y); s.z = f2bf(v.z); s.w = f2bf(v.w);
      *(short4*)(seq_lds + sr * 136 + sc) = s;
    }
    __syncthreads();

    // ---- layer 0 gates ----
    f32x4 acc[4][2];
#pragma unroll
    for (int g = 0; g < 4; ++g)
#pragma unroll
      for (int u = 0; u < 2; ++u) acc[g][u] = bcast4(b0v[g][u]);
    gemm_gates<RD_>(seq_lds + l15 * 136 + quad * 8, wih0_l, RD_, acc);
    gemm_gates<RH_>(h0_lds[p] + l15 * 264 + quad * 8, whh0_l, RH_, acc);

    short* h0w = h0_lds[1 - p];
#pragma unroll
    for (int u = 0; u < 2; ++u) {
      int j = w * 32 + u * 16 + l15;
#pragma unroll
      for (int r = 0; r < 4; ++r) {
        float cn = sigf(acc[1][u][r]) * c0s[u][r] + sigf(acc[0][u][r]) * tanh_f(acc[2][u][r]);
        c0s[u][r] = cn;
        float h = sigf(acc[3][u][r]) * tanh_f(cn);
        h0w[(quad * 4 + r) * 264 + j] = f2bf(h);
      }
    }
    __syncthreads();

    // ---- layer 1 gates ----
#pragma unroll
    for (int g = 0; g < 4; ++g)
#pragma unroll
      for (int u = 0; u < 2; ++u) acc[g][u] = bcast4(b1v[g][u]);
    gemm_gates<RH_>(h0w + l15 * 264 + quad * 8, wih1_l, RH_, acc);
    gemm_gates<RH_>(h1_lds[p] + l15 * 264 + quad * 8, whh1_l, RH_, acc);

    short* h1w = h1_lds[1 - p];
#pragma unroll
    for (int u = 0; u < 2; ++u) {
      int j = w * 32 + u * 16 + l15;
#pragma unroll
      for (int r = 0; r < 4; ++r) {
        float cn = sigf(acc[1][u][r]) * c1s[u][r] + sigf(acc[0][u][r]) * tanh_f(acc[2][u][r]);
        c1s[u][r] = cn;
        float h = sigf(acc[3][u][r]) * tanh_f(cn);
        h1w[(quad * 4 + r) * 264 + j] = f2bf(h);
      }
    }
    __syncthreads();
  }

  const short* h1f = h1_lds[1 - ((T_ - 1) & 1)];

  // ---- r-MLP: r1 = relu(h1 @ rW1 + rb1), wave w owns n in [64w,64w+64) ----
  {
    f32x4 racc[4];
#pragma unroll
    for (int u = 0; u < 4; ++u) racc[u] = bcast4(rb1[w * 64 + u * 16 + l15]);
    gemm_nt<RH_, 4>(h1f + l15 * 264 + quad * 8, rW1T + (w * 64 + l15) * RH_ + quad * 8, RH_, racc);
#pragma unroll
    for (int u = 0; u < 4; ++u)
#pragma unroll
      for (int r = 0; r < 4; ++r)
        r1_lds[(quad * 4 + r) * 520 + w * 64 + u * 16 + l15] = f2bf(fmaxf(racc[u][r], 0.0f));
  }
  __syncthreads();
  // ---- r2 = r1 @ rW2 + rb2 -> z[:,128..383]; also stage u_in ----
  {
    f32x4 racc[2];
#pragma unroll
    for (int u = 0; u < 2; ++u) racc[u] = bcast4(rb2[w * 32 + u * 16 + l15]);
    gemm_nt<512, 2>(r1_lds + l15 * 520 + quad * 8, rW2T + (w * 32 + l15) * 512 + quad * 8, 512, racc);
#pragma unroll
    for (int u = 0; u < 2; ++u)
#pragma unroll
      for (int r = 0; r < 4; ++r)
        z_out[(size_t)(row0 + quad * 4 + r) * EIN_ + 128 + w * 32 + u * 16 + l15] =
            f2bf(racc[u][r]);
  }
  if (tid < 384) {
    int r = tid / 24, c4 = (tid % 24) * 4;
    float4 v;
    if (c4 < 64) v = *(const float4*)(uemb + (size_t)user_ids[row0 + r] * 64 + c4);
    else         v = *(const float4*)(user_data + (row0 + r) * 32 + (c4 - 64));
    short4 s;
    s.x = f2bf(v.x); s.y = f2bf(v.y); s.z = f2bf(v.z); s.w = f2bf(v.w);
    *(short4*)(seq_lds + r * 136 + c4) = s;
  }
  __syncthreads();
  // ---- u1 = relu(u_in @ uW1 + ub1): N=192, waves 0..5 ----
  if (w < 6) {
    f32x4 uacc[2];
#pragma unroll
    for (int u = 0; u < 2; ++u) uacc[u] = bcast4(ub1[w * 32 + u * 16 + l15]);
    gemm_nt<UIN_, 2>(seq_lds + l15 * 136 + quad * 8, uW1T + (w * 32 + l15) * UIN_ + quad * 8,
                     UIN_, uacc);
#pragma unroll
    for (int u = 0; u < 2; ++u)
#pragma unroll
      for (int r = 0; r < 4; ++r)
        r1_lds[(quad * 4 + r) * 200 + w * 32 + u * 16 + l15] = f2bf(fmaxf(uacc[u][r], 0.0f));
  }
  __syncthreads();
  // ---- u2 = u1 @ uW2 + ub2 -> z[:,0..127]: N=128, 8 waves x 1 tile ----
  {
    f32x4 uacc = bcast4(ub2[w * 16 + l15]);
    gemm_nt<192, 1>(r1_lds + l15 * 200 + quad * 8, uW2T + (w * 16 + l15) * 192 + quad * 8, 192,
                    &uacc);
#pragma unroll
    for (int r = 0; r < 4; ++r)
      z_out[(size_t)(row0 + quad * 4 + r) * EIN_ + w * 16 + l15] = f2bf(uacc[r]);
  }
}

// ---------------- expert MoE: out[b,e] = relu(z@W1[e]+b1[e]) @ W2[e] + b2[e] ----------------
// 512 blocks = (e = bid>>3, mc = bid&7). 512 threads, waves as 4(m) x 2(n).
// A-frags (32 rows x K=384) register-resident; B staged in LDS 128-k chunks.
__global__ __launch_bounds__(512) void expert_mlp(
    const short* __restrict__ z, const short* __restrict__ eW1T,
    const float* __restrict__ eb1, const float* __restrict__ eW2,
    const float* __restrict__ eb2, float* __restrict__ out) {
  __shared__ __align__(16) short blds[128 * 136];
  __shared__ float outpart[2][128];

  const int e = blockIdx.x >> 3;
  const int mc = blockIdx.x & 7;
  const int tid = threadIdx.x, w = tid >> 6, lane = tid & 63;
  const int l15 = lane & 15, quad = lane >> 4;
  const int wm = w >> 1, wn = w & 1;
  const int rbase = mc * 128 + wm * 32;

  bf16x8 afr[2][12];
#pragma unroll
  for (int mt = 0; mt < 2; ++mt)
#pragma unroll
    for (int ks = 0; ks < 12; ++ks)
      afr[mt][ks] =
          *(const bf16x8*)(z + (size_t)(rbase + mt * 16 + l15) * EIN_ + ks * 32 + quad * 8);

  const short* w1e = eW1T + (size_t)e * EH_ * EIN_;
  float osum[2][4] = {{0,0,0,0},{0,0,0,0}};

  for (int nc = 0; nc < 12; ++nc) {
    f32x4 acc[2][4];
#pragma unroll
    for (int u = 0; u < 4; ++u) {
      float bv = eb1[e * EH_ + nc * 128 + wn * 64 + u * 16 + l15];
      acc[0][u] = bcast4(bv);
      acc[1][u] = bcast4(bv);
    }
#pragma unroll
    for (int kc = 0; kc < 3; ++kc) {
      __syncthreads();  // previous chunk fully consumed
#pragma unroll
      for (int q = 0; q < 4; ++q) {
        int rr = q * 32 + (tid >> 4);
        int ko = (tid & 15) * 8;
        *(bf16x8*)(blds + rr * 136 + ko) =
            *(const bf16x8*)(w1e + (size_t)(nc * 128 + rr) * EIN_ + kc * 128 + ko);
      }
      __syncthreads();
#pragma unroll
      for (int ks = 0; ks < 4; ++ks) {
        bf16x8 bfv[4];
#pragma unroll
        for (int u = 0; u < 4; ++u)
          bfv[u] = *(const bf16x8*)(blds + (wn * 64 + u * 16 + l15) * 136 + ks * 32 + quad * 8);
#pragma unroll
        for (int mt = 0; mt < 2; ++mt) {
          bf16x8 af = afr[mt][kc * 4 + ks];
#pragma unroll
          for (int u = 0; u < 4; ++u)
            acc[mt][u] = __builtin_amdgcn_mfma_f32_16x16x32_bf16(af, bfv[u], acc[mt][u], 0, 0, 0);
        }
      }
    }
    // epilogue: relu * W2, accumulate per-lane over this n-chunk
#pragma unroll
    for (int u = 0; u < 4; ++u) {
      float w2v = eW2[e * EH_ + nc * 128 + wn * 64 + u * 16 + l15];
#pragma unroll
      for (int mt = 0; mt < 2; ++mt)
#pragma unroll
        for (int r = 0; r < 4; ++r) osum[mt][r] += fmaxf(acc[mt][u][r], 0.0f) * w2v;
    }
  }
  // reduce across the 16 columns held by lanes (l15 bits)
#pragma unroll
  for (int mt = 0; mt < 2; ++mt)
#pragma unroll
    for (int r = 0; r < 4; ++r) {
      float v = osum[mt][r];
      v += __shfl_xor(v, 1);
      v += __shfl_xor(v, 2);
      v += __shfl_xor(v, 4);
      v += __shfl_xor(v, 8);
      if (l15 == 0) outpart[wn][wm * 32 + mt * 16 + quad * 4 + r] = v;
    }
  __syncthreads();
  if (tid < 128) {
    float v = outpart[0][tid] + outpart[1][tid] + eb2[e];
    out[(size_t)(mc * 128 + tid) * E_ + e] = v;
  }
}

// ---------------- launch ----------------
extern "C" void kernel_launch(void* const* d_in, const int* in_sizes, int n_in, void* d_out,
                              int out_size, void* d_ws, size_t ws_size, hipStream_t stream) {
  (void)in_sizes; (void)n_in; (void)out_size; (void)ws_size;
  const int*   ratings = (const int*)d_in[0];
  const int*   uids    = (const int*)d_in[1];
  const float* udata   = (const float*)d_in[2];
  const float* remb    = (const float*)d_in[3];
  const float* uemb    = (const float*)d_in[4];
  const float* wih0    = (const float*)d_in[5];
  const float* whh0    = (const float*)d_in[6];
  const float* bih0    = (const float*)d_in[7];
  const float* bhh0    = (const float*)d_in[8];
  const float* wih1    = (const float*)d_in[9];
  const float* whh1    = (const float*)d_in[10];
  const float* bih1    = (const float*)d_in[11];
  const float* bhh1    = (const float*)d_in[12];
  const float* rW1     = (const float*)d_in[13];
  const float* rb1     = (const float*)d_in[14];
  const float* rW2     = (const float*)d_in[15];
  const float* rb2     = (const float*)d_in[16];
  const float* uW1     = (const float*)d_in[17];
  const float* ub1     = (const float*)d_in[18];
  const float* uW2     = (const float*)d_in[19];
  const float* ub2     = (const float*)d_in[20];
  const float* eW1     = (const float*)d_in[21];
  const float* eb1     = (const float*)d_in[22];
  const float* eW2     = (const float*)d_in[23];
  const float* eb2     = (const float*)d_in[24];
  float* out = (float*)d_out;

  char* ws = (char*)d_ws;
  short* WIH0 = (short*)(ws + 0);        // 1024x128 bf16
  short* WHH0 = (short*)(ws + 262144);   // 1024x256
  short* WIH1 = (short*)(ws + 786432);   // 1024x256
  short* WHH1 = (short*)(ws + 1310720);  // 1024x256
  short* RW1T = (short*)(ws + 1835008);  // 512x256
  short* RW2T = (short*)(ws + 2097152);  // 256x512
  short* UW1T = (short*)(ws + 2359296);  // 192x96
  short* UW2T = (short*)(ws + 2396160);  // 128x192
  float* B0   = (float*)(ws + 2445312);  // 1024 f32
  float* B1   = (float*)(ws + 2449408);  // 1024 f32
  short* Z    = (short*)(ws + 2453504);  // 1024x384 bf16
  short* EW1T = (short*)(ws + 3239936);  // 64x1536x384 bf16 (75.5 MB)

  hipLaunchKernelGGL(prep_cast, dim3(1024), dim3(256), 0, stream, wih0, whh0, wih1, whh1, bih0,
                     bhh0, bih1, bhh1, WIH0, WHH0, WIH1, WHH1, B0, B1);
  hipLaunchKernelGGL(transpose_cast, dim3(8, 16, 1), dim3(256), 0, stream, rW1, RW1T, 256, 512);
  hipLaunchKernelGGL(transpose_cast, dim3(16, 8, 1), dim3(256), 0, stream, rW2, RW2T, 512, 256);
  hipLaunchKernelGGL(transpose_cast, dim3(3, 6, 1), dim3(256), 0, stream, uW1, UW1T, 96, 192);
  hipLaunchKernelGGL(transpose_cast, dim3(6, 4, 1), dim3(256), 0, stream, uW2, UW2T, 192, 128);
  hipLaunchKernelGGL(transpose_cast, dim3(12, 48, 64), dim3(256), 0, stream, eW1, EW1T, 384, 1536);
  hipLaunchKernelGGL(lstm_fused, dim3(64), dim3(512), 0, stream, ratings, uids, udata, remb, uemb,
                     WIH0, WHH0, WIH1, WHH1, B0, B1, RW1T, rb1, RW2T, rb2, UW1T, ub1, UW2T, ub2, Z);
  hipLaunchKernelGGL(expert_mlp, dim3(512), dim3(512), 0, stream, Z, EW1T, eb1, eW2, eb2, out);
}

// Round 2
// 1152.003 us; speedup vs baseline: 3.1834x; 3.1834x over previous
//
#include <hip/hip_runtime.h>
#include <hip/hip_bf16.h>

#define B_    1024
#define T_    50
#define RD_   128
#define RH_   256
#define UIN_  96
#define EIN_  384
#define EH_   1536
#define E_    64

typedef __attribute__((ext_vector_type(8))) short bf16x8;
typedef __attribute__((ext_vector_type(4))) float f32x4;

__device__ __forceinline__ short f2bf(float x) {
  unsigned u = __float_as_uint(x);
  unsigned r = (u + 0x7fffu + ((u >> 16) & 1u)) >> 16;
  return (short)(r & 0xffffu);
}

__device__ __forceinline__ f32x4 bcast4(float v) { f32x4 x = {v, v, v, v}; return x; }

__device__ __forceinline__ float sigf(float x) {
  return __builtin_amdgcn_rcpf(1.0f + __expf(-x));
}
__device__ __forceinline__ float tanh_f(float x) {
  float e = __expf(-2.0f * fabsf(x));
  float t = (1.0f - e) * __builtin_amdgcn_rcpf(1.0f + e);
  return x >= 0.0f ? t : -t;
}

// ---------------- prep: cast LSTM weights to bf16, sum biases ----------------
__global__ void prep_cast(const float* __restrict__ wih0, const float* __restrict__ whh0,
                          const float* __restrict__ wih1, const float* __restrict__ whh1,
                          const float* __restrict__ bi0, const float* __restrict__ bh0,
                          const float* __restrict__ bi1, const float* __restrict__ bh1,
                          short* __restrict__ o_ih0, short* __restrict__ o_hh0,
                          short* __restrict__ o_ih1, short* __restrict__ o_hh1,
                          float* __restrict__ ob0, float* __restrict__ ob1) {
  int i = blockIdx.x * blockDim.x + threadIdx.x;
  if (i < 1024 * 128) o_ih0[i] = f2bf(wih0[i]);
  if (i < 1024 * 256) {
    o_hh0[i] = f2bf(whh0[i]);
    o_ih1[i] = f2bf(wih1[i]);
    o_hh1[i] = f2bf(whh1[i]);
  }
  if (i < 1024) { ob0[i] = bi0[i] + bh0[i]; ob1[i] = bi1[i] + bh1[i]; }
}

// ---------------- generic transpose + cast: src[R][C] f32 -> dst[C][R] bf16 ----------------
__global__ void transpose_cast(const float* __restrict__ src, short* __restrict__ dst,
                               int R, int C) {
  __shared__ float tile[32][33];
  size_t boff = (size_t)blockIdx.z * (size_t)R * (size_t)C;
  int tx = threadIdx.x & 31, ty = threadIdx.x >> 5;
  int r0 = blockIdx.x * 32, c0 = blockIdx.y * 32;
#pragma unroll
  for (int q = 0; q < 4; ++q) {
    int r = r0 + ty + q * 8, c = c0 + tx;
    if (r < R && c < C) tile[ty + q * 8][tx] = src[boff + (size_t)r * C + c];
  }
  __syncthreads();
#pragma unroll
  for (int q = 0; q < 4; ++q) {
    int cr = c0 + ty + q * 8, cc = r0 + tx;
    if (cr < C && cc < R) dst[boff + (size_t)cr * R + cc] = f2bf(tile[tx][ty + q * 8]);
  }
}

// ---------------- gemm helper (tail MLPs) ----------------
template<int KTOT, int NT>
__device__ __forceinline__ void gemm_nt(const short* a_lane, const short* w_lane, int ldw,
                                        f32x4* acc) {
#pragma unroll
  for (int k = 0; k < KTOT; k += 32) {
    bf16x8 af = *(const bf16x8*)(a_lane + k);
#pragma unroll
    for (int u = 0; u < NT; ++u) {
      bf16x8 bf = *(const bf16x8*)(w_lane + u * 16 * ldw + k);
      acc[u] = __builtin_amdgcn_mfma_f32_16x16x32_bf16(af, bf, acc[u], 0, 0, 0);
    }
  }
}

// ---------------- K1: xg0 = gather(remb)[B*T,128] @ Wih0^T + b ----------------
// grid (400, 4), 512 thr. wave = wm(4: 32-row slice) x wn(2: 128-col slice)
__global__ __launch_bounds__(512) void xg_gather_gemm(
    const int* __restrict__ ratings, const float* __restrict__ remb,
    const short* __restrict__ WihT, const float* __restrict__ bias,
    float* __restrict__ xg) {
  __shared__ __align__(16) short slab[256 * 140];  // B^T slice [256 n][128 k], pad 140
  const int tid = threadIdx.x, w = tid >> 6, lane = tid & 63;
  const int l15 = lane & 15, quad = lane >> 4;
  const int wm = w & 3, wn = w >> 2;
  const int mbase = blockIdx.x * 128;
  const int nbase = blockIdx.y * 256;

  for (int j = tid; j < 256 * 16; j += 512) {
    int r = j >> 4, c8 = (j & 15) * 8;
    *(bf16x8*)(slab + r * 140 + c8) = *(const bf16x8*)(WihT + (nbase + r) * RD_ + c8);
  }
  // register A-fragments: gather + f32->bf16
  bf16x8 af[2][4];
#pragma unroll
  for (int mt = 0; mt < 2; ++mt) {
    int flat = mbase + wm * 32 + mt * 16 + l15;
    int idx = ratings[flat];
    const float* ap = remb + (size_t)idx * RD_ + quad * 8;
#pragma unroll
    for (int kc = 0; kc < 4; ++kc) {
      float4 v0 = *(const float4*)(ap + kc * 32);
      float4 v1 = *(const float4*)(ap + kc * 32 + 4);
      bf16x8 a;
      a[0] = f2bf(v0.x); a[1] = f2bf(v0.y); a[2] = f2bf(v0.z); a[3] = f2bf(v0.w);
      a[4] = f2bf(v1.x); a[5] = f2bf(v1.y); a[6] = f2bf(v1.z); a[7] = f2bf(v1.w);
      af[mt][kc] = a;
    }
  }
  __syncthreads();
#pragma unroll
  for (int nt = 0; nt < 8; ++nt) {
    int ncol = wn * 128 + nt * 16 + l15;
    int col = nbase + ncol;
    f32x4 acc0 = bcast4(bias[col]), acc1 = acc0;
#pragma unroll
    for (int kc = 0; kc < 4; ++kc) {
      bf16x8 bf = *(const bf16x8*)(slab + ncol * 140 + kc * 32 + quad * 8);
      acc0 = __builtin_amdgcn_mfma_f32_16x16x32_bf16(af[0][kc], bf, acc0, 0, 0, 0);
      acc1 = __builtin_amdgcn_mfma_f32_16x16x32_bf16(af[1][kc], bf, acc1, 0, 0, 0);
    }
#pragma unroll
    for (int r = 0; r < 4; ++r) {
      xg[(size_t)(mbase + wm * 32 + quad * 4 + r) * 1024 + col] = acc0[r];
      xg[(size_t)(mbase + wm * 32 + 16 + quad * 4 + r) * 1024 + col] = acc1[r];
    }
  }
}

// ---------------- K3: xg1 = h0_all[B*T,256] @ Wih1^T + b ----------------
__global__ __launch_bounds__(512) void xg_h_gemm(
    const short* __restrict__ h_all, const short* __restrict__ WihT,
    const float* __restrict__ bias, float* __restrict__ xg) {
  __shared__ __align__(16) short slab[256 * 268];  // [256 n][256 k] pad 268
  const int tid = threadIdx.x, w = tid >> 6, lane = tid & 63;
  const int l15 = lane & 15, quad = lane >> 4;
  const int wm = w & 3, wn = w >> 2;
  const int mbase = blockIdx.x * 128;
  const int nbase = blockIdx.y * 256;

  for (int j = tid; j < 256 * 32; j += 512) {
    int r = j >> 5, c8 = (j & 31) * 8;
    *(bf16x8*)(slab + r * 268 + c8) = *(const bf16x8*)(WihT + (nbase + r) * RH_ + c8);
  }
  bf16x8 af[2][8];
#pragma unroll
  for (int mt = 0; mt < 2; ++mt) {
    const short* ap = h_all + (size_t)(mbase + wm * 32 + mt * 16 + l15) * RH_ + quad * 8;
#pragma unroll
    for (int kc = 0; kc < 8; ++kc) af[mt][kc] = *(const bf16x8*)(ap + kc * 32);
  }
  __syncthreads();
#pragma unroll
  for (int nt = 0; nt < 8; ++nt) {
    int ncol = wn * 128 + nt * 16 + l15;
    int col = nbase + ncol;
    f32x4 acc0 = bcast4(bias[col]), acc1 = acc0;
#pragma unroll
    for (int kc = 0; kc < 8; ++kc) {
      bf16x8 bf = *(const bf16x8*)(slab + ncol * 268 + kc * 32 + quad * 8);
      acc0 = __builtin_amdgcn_mfma_f32_16x16x32_bf16(af[0][kc], bf, acc0, 0, 0, 0);
      acc1 = __builtin_amdgcn_mfma_f32_16x16x32_bf16(af[1][kc], bf, acc1, 0, 0, 0);
    }
#pragma unroll
    for (int r = 0; r < 4; ++r) {
      xg[(size_t)(mbase + wm * 32 + quad * 4 + r) * 1024 + col] = acc0[r];
      xg[(size_t)(mbase + wm * 32 + 16 + quad * 4 + r) * 1024 + col] = acc1[r];
    }
  }
}

// ---------------- recurrence core (shared by both layers via macro-ish duplication) ----
// 64 blocks x 16 rows, 512 thr. wave w owns hidden units [32w,32w+32).
// Whh kc 0..3 in 128 persistent VGPRs, kc 4..5 in LDS slab, kc 6..7 streamed from L2.
#define REC_PROLOGUE()                                                                   \
  __shared__ __align__(16) short hl[2][16 * 268];                                        \
  __shared__ __align__(16) short slab[1024 * 68];                                        \
  const int tid = threadIdx.x, w = tid >> 6, lane = tid & 63;                            \
  const int l15 = lane & 15, quad = lane >> 4;                                           \
  const int row0 = blockIdx.x * 16;                                                      \
  for (int i = tid; i < 16 * 268; i += 512) { hl[0][i] = 0; hl[1][i] = 0; }              \
  for (int i = tid; i < 1024 * 8; i += 512) {                                            \
    int r = i >> 3, c8 = (i & 7) * 8;                                                    \
    *(bf16x8*)(slab + r * 68 + c8) = *(const bf16x8*)(Whh + r * RH_ + 128 + c8);         \
  }                                                                                      \
  bf16x8 wreg[4][2][4];                                                                  \
  _Pragma("unroll") for (int g = 0; g < 4; ++g)                                          \
  _Pragma("unroll") for (int u = 0; u < 2; ++u)                                          \
  _Pragma("unroll") for (int kc = 0; kc < 4; ++kc)                                       \
      wreg[g][u][kc] = *(const bf16x8*)(Whh + (g * 256 + w * 32 + u * 16 + l15) * RH_ +  \
                                        kc * 32 + quad * 8);                             \
  float cs[2][4] = {{0, 0, 0, 0}, {0, 0, 0, 0}};                                         \
  __syncthreads();

#define REC_STEP(acc, t)                                                                 \
  {                                                                                      \
    _Pragma("unroll") for (int g = 0; g < 4; ++g)                                        \
    _Pragma("unroll") for (int u = 0; u < 2; ++u) {                                      \
      const float* xp = xg + ((size_t)(row0 + quad * 4) * T_ + (t)) * 1024 + g * 256 +   \
                        w * 32 + u * 16 + l15;                                           \
      _Pragma("unroll") for (int r = 0; r < 4; ++r)                                      \
          acc[g][u][r] = xp[(size_t)r * T_ * 1024];                                      \
    }                                                                                    \
    const short* al = hl[(t) & 1] + l15 * 268;                                           \
    _Pragma("unroll") for (int kc = 0; kc < 8; ++kc) {                                   \
      bf16x8 afh = *(const bf16x8*)(al + kc * 32 + quad * 8);                            \
      if (kc < 4) {                                                                      \
        _Pragma("unroll") for (int g = 0; g < 4; ++g)                                    \
        _Pragma("unroll") for (int u = 0; u < 2; ++u)                                    \
            acc[g][u] = __builtin_amdgcn_mfma_f32_16x16x32_bf16(afh, wreg[g][u][kc],     \
                                                                acc[g][u], 0, 0, 0);     \
      } else if (kc < 6) {                                                               \
        _Pragma("unroll") for (int g = 0; g < 4; ++g)                                    \
        _Pragma("unroll") for (int u = 0; u < 2; ++u) {                                  \
          bf16x8 bfv = *(const bf16x8*)(slab + (g * 256 + w * 32 + u * 16 + l15) * 68 +  \
                                        (kc - 4) * 32 + quad * 8);                       \
          acc[g][u] = __builtin_amdgcn_mfma_f32_16x16x32_bf16(afh, bfv, acc[g][u], 0, 0, 0); \
        }                                                                                \
      } else {                                                                           \
        _Pragma("unroll") for (int g = 0; g < 4; ++g)                                    \
        _Pragma("unroll") for (int u = 0; u < 2; ++u) {                                  \
          bf16x8 bfv = *(const bf16x8*)(Whh + (g * 256 + w * 32 + u * 16 + l15) * RH_ +  \
                                        kc * 32 + quad * 8);                             \
          acc[g][u] = __builtin_amdgcn_mfma_f32_16x16x32_bf16(afh, bfv, acc[g][u], 0, 0, 0); \
        }                                                                                \
      }                                                                                  \
    }                                                                                    \
  }

// K2: layer-0 recurrence, stores h for all t
__global__ __launch_bounds__(512, 2) void lstm_rec_store(
    const float* __restrict__ xg, const short* __restrict__ Whh,
    short* __restrict__ h_all) {
  REC_PROLOGUE()
  for (int t = 0; t < T_; ++t) {
    f32x4 acc[4][2];
    REC_STEP(acc, t)
    short* hw = hl[1 - (t & 1)];
#pragma unroll
    for (int u = 0; u < 2; ++u) {
      int j = w * 32 + u * 16 + l15;
#pragma unroll
      for (int r = 0; r < 4; ++r) {
        float cn = sigf(acc[1][u][r]) * cs[u][r] + sigf(acc[0][u][r]) * tanh_f(acc[2][u][r]);
        cs[u][r] = cn;
        short hb = f2bf(sigf(acc[3][u][r]) * tanh_f(cn));
        hw[(quad * 4 + r) * 268 + j] = hb;
        h_all[((size_t)(row0 + quad * 4 + r) * T_ + t) * RH_ + j] = hb;
      }
    }
    __syncthreads();
  }
}

// K4: layer-1 recurrence + fused r-MLP / u-MLP tail -> z
__global__ __launch_bounds__(512, 2) void lstm_rec_tail(
    const float* __restrict__ xg, const short* __restrict__ Whh,
    const int* __restrict__ user_ids, const float* __restrict__ user_data,
    const float* __restrict__ uemb,
    const short* __restrict__ rW1T, const float* __restrict__ rb1,
    const short* __restrict__ rW2T, const float* __restrict__ rb2,
    const short* __restrict__ uW1T, const float* __restrict__ ub1,
    const short* __restrict__ uW2T, const float* __restrict__ ub2,
    short* __restrict__ z_out) {
  REC_PROLOGUE()
  for (int t = 0; t < T_; ++t) {
    f32x4 acc[4][2];
    REC_STEP(acc, t)
    short* hw = hl[1 - (t & 1)];
#pragma unroll
    for (int u = 0; u < 2; ++u) {
      int j = w * 32 + u * 16 + l15;
#pragma unroll
      for (int r = 0; r < 4; ++r) {
        float cn = sigf(acc[1][u][r]) * cs[u][r] + sigf(acc[0][u][r]) * tanh_f(acc[2][u][r]);
        cs[u][r] = cn;
        hw[(quad * 4 + r) * 268 + j] = f2bf(sigf(acc[3][u][r]) * tanh_f(cn));
      }
    }
    __syncthreads();
  }

  const short* h1f = hl[1 - ((T_ - 1) & 1)];
  short* r1_lds = slab;            // 16*520 shorts (weights no longer needed)
  short* seq2 = slab + 16 * 520;   // 16*136 shorts

  // r1 = relu(h1 @ rW1 + rb1): wave w owns n in [64w, 64w+64)
  {
    f32x4 racc[4];
#pragma unroll
    for (int u = 0; u < 4; ++u) racc[u] = bcast4(rb1[w * 64 + u * 16 + l15]);
    gemm_nt<RH_, 4>(h1f + l15 * 268 + quad * 8, rW1T + (w * 64 + l15) * RH_ + quad * 8, RH_, racc);
#pragma unroll
    for (int u = 0; u < 4; ++u)
#pragma unroll
      for (int r = 0; r < 4; ++r)
        r1_lds[(quad * 4 + r) * 520 + w * 64 + u * 16 + l15] = f2bf(fmaxf(racc[u][r], 0.0f));
  }
  __syncthreads();
  // r2 -> z[:,128..384)
  {
    f32x4 racc[2];
#pragma unroll
    for (int u = 0; u < 2; ++u) racc[u] = bcast4(rb2[w * 32 + u * 16 + l15]);
    gemm_nt<512, 2>(r1_lds + l15 * 520 + quad * 8, rW2T + (w * 32 + l15) * 512 + quad * 8, 512, racc);
#pragma unroll
    for (int u = 0; u < 2; ++u)
#pragma unroll
      for (int r = 0; r < 4; ++r)
        z_out[(size_t)(row0 + quad * 4 + r) * EIN_ + 128 + w * 32 + u * 16 + l15] =
            f2bf(racc[u][r]);
  }
  if (tid < 384) {
    int r = tid / 24, c4 = (tid % 24) * 4;
    float4 v;
    if (c4 < 64) v = *(const float4*)(uemb + (size_t)user_ids[row0 + r] * 64 + c4);
    else         v = *(const float4*)(user_data + (row0 + r) * 32 + (c4 - 64));
    short4 s;
    s.x = f2bf(v.x); s.y = f2bf(v.y); s.z = f2bf(v.z); s.w = f2bf(v.w);
    *(short4*)(seq2 + r * 136 + c4) = s;
  }
  __syncthreads();
  // u1 = relu(u_in @ uW1 + ub1): N=192, waves 0..5
  if (w < 6) {
    f32x4 uacc[2];
#pragma unroll
    for (int u = 0; u < 2; ++u) uacc[u] = bcast4(ub1[w * 32 + u * 16 + l15]);
    gemm_nt<UIN_, 2>(seq2 + l15 * 136 + quad * 8, uW1T + (w * 32 + l15) * UIN_ + quad * 8,
                     UIN_, uacc);
#pragma unroll
    for (int u = 0; u < 2; ++u)
#pragma unroll
      for (int r = 0; r < 4; ++r)
        r1_lds[(quad * 4 + r) * 200 + w * 32 + u * 16 + l15] = f2bf(fmaxf(uacc[u][r], 0.0f));
  }
  __syncthreads();
  // u2 -> z[:,0..128)
  {
    f32x4 uacc = bcast4(ub2[w * 16 + l15]);
    gemm_nt<192, 1>(r1_lds + l15 * 200 + quad * 8, uW2T + (w * 16 + l15) * 192 + quad * 8, 192,
                    &uacc);
#pragma unroll
    for (int r = 0; r < 4; ++r)
      z_out[(size_t)(row0 + quad * 4 + r) * EIN_ + w * 16 + l15] = f2bf(uacc[r]);
  }
}

// ---------------- expert MoE: out[b,e] = relu(z@W1[e]+b1[e]) @ W2[e] + b2[e] ----------------
__global__ __launch_bounds__(512) void expert_mlp(
    const short* __restrict__ z, const short* __restrict__ eW1T,
    const float* __restrict__ eb1, const float* __restrict__ eW2,
    const float* __restrict__ eb2, float* __restrict__ out) {
  __shared__ __align__(16) short blds[128 * 136];
  __shared__ float outpart[2][128];

  const int e = blockIdx.x >> 3;
  const int mc = blockIdx.x & 7;
  const int tid = threadIdx.x, w = tid >> 6, lane = tid & 63;
  const int l15 = lane & 15, quad = lane >> 4;
  const int wm = w >> 1, wn = w & 1;
  const int rbase = mc * 128 + wm * 32;

  bf16x8 afr[2][12];
#pragma unroll
  for (int mt = 0; mt < 2; ++mt)
#pragma unroll
    for (int ks = 0; ks < 12; ++ks)
      afr[mt][ks] =
          *(const bf16x8*)(z + (size_t)(rbase + mt * 16 + l15) * EIN_ + ks * 32 + quad * 8);

  const short* w1e = eW1T + (size_t)e * EH_ * EIN_;
  float osum[2][4] = {{0,0,0,0},{0,0,0,0}};

  for (int nc = 0; nc < 12; ++nc) {
    f32x4 acc[2][4];
#pragma unroll
    for (int u = 0; u < 4; ++u) {
      float bv = eb1[e * EH_ + nc * 128 + wn * 64 + u * 16 + l15];
      acc[0][u] = bcast4(bv);
      acc[1][u] = bcast4(bv);
    }
#pragma unroll
    for (int kc = 0; kc < 3; ++kc) {
      __syncthreads();
#pragma unroll
      for (int q = 0; q < 4; ++q) {
        int rr = q * 32 + (tid >> 4);
        int ko = (tid & 15) * 8;
        *(bf16x8*)(blds + rr * 136 + ko) =
            *(const bf16x8*)(w1e + (size_t)(nc * 128 + rr) * EIN_ + kc * 128 + ko);
      }
      __syncthreads();
#pragma unroll
      for (int ks = 0; ks < 4; ++ks) {
        bf16x8 bfv[4];
#pragma unroll
        for (int u = 0; u < 4; ++u)
          bfv[u] = *(const bf16x8*)(blds + (wn * 64 + u * 16 + l15) * 136 + ks * 32 + quad * 8);
#pragma unroll
        for (int mt = 0; mt < 2; ++mt) {
          bf16x8 af = afr[mt][kc * 4 + ks];
#pragma unroll
          for (int u = 0; u < 4; ++u)
            acc[mt][u] = __builtin_amdgcn_mfma_f32_16x16x32_bf16(af, bfv[u], acc[mt][u], 0, 0, 0);
        }
      }
    }
#pragma unroll
    for (int u = 0; u < 4; ++u) {
      float w2v = eW2[e * EH_ + nc * 128 + wn * 64 + u * 16 + l15];
#pragma unroll
      for (int mt = 0; mt < 2; ++mt)
#pragma unroll
        for (int r = 0; r < 4; ++r) osum[mt][r] += fmaxf(acc[mt][u][r], 0.0f) * w2v;
    }
  }
#pragma unroll
  for (int mt = 0; mt < 2; ++mt)
#pragma unroll
    for (int r = 0; r < 4; ++r) {
      float v = osum[mt][r];
      v += __shfl_xor(v, 1);
      v += __shfl_xor(v, 2);
      v += __shfl_xor(v, 4);
      v += __shfl_xor(v, 8);
      if (l15 == 0) outpart[wn][wm * 32 + mt * 16 + quad * 4 + r] = v;
    }
  __syncthreads();
  if (tid < 128) {
    float v = outpart[0][tid] + outpart[1][tid] + eb2[e];
    out[(size_t)(mc * 128 + tid) * E_ + e] = v;
  }
}

// ---------------- launch ----------------
extern "C" void kernel_launch(void* const* d_in, const int* in_sizes, int n_in, void* d_out,
                              int out_size, void* d_ws, size_t ws_size, hipStream_t stream) {
  (void)in_sizes; (void)n_in; (void)out_size; (void)ws_size;
  const int*   ratings = (const int*)d_in[0];
  const int*   uids    = (const int*)d_in[1];
  const float* udata   = (const float*)d_in[2];
  const float* remb    = (const float*)d_in[3];
  const float* uemb    = (const float*)d_in[4];
  const float* wih0    = (const float*)d_in[5];
  const float* whh0    = (const float*)d_in[6];
  const float* bih0    = (const float*)d_in[7];
  const float* bhh0    = (const float*)d_in[8];
  const float* wih1    = (const float*)d_in[9];
  const float* whh1    = (const float*)d_in[10];
  const float* bih1    = (const float*)d_in[11];
  const float* bhh1    = (const float*)d_in[12];
  const float* rW1     = (const float*)d_in[13];
  const float* rb1     = (const float*)d_in[14];
  const float* rW2     = (const float*)d_in[15];
  const float* rb2     = (const float*)d_in[16];
  const float* uW1     = (const float*)d_in[17];
  const float* ub1     = (const float*)d_in[18];
  const float* uW2     = (const float*)d_in[19];
  const float* ub2     = (const float*)d_in[20];
  const float* eW1     = (const float*)d_in[21];
  const float* eb1     = (const float*)d_in[22];
  const float* eW2     = (const float*)d_in[23];
  const float* eb2     = (const float*)d_in[24];
  float* out = (float*)d_out;

  char* ws = (char*)d_ws;
  short* WIH0 = (short*)(ws + 0);         // 1024x128 bf16
  short* WHH0 = (short*)(ws + 262144);    // 1024x256
  short* WIH1 = (short*)(ws + 786432);    // 1024x256
  short* WHH1 = (short*)(ws + 1310720);   // 1024x256
  short* RW1T = (short*)(ws + 1835008);   // 512x256
  short* RW2T = (short*)(ws + 2097152);   // 256x512
  short* UW1T = (short*)(ws + 2359296);   // 192x96
  short* UW2T = (short*)(ws + 2396160);   // 128x192
  float* B0   = (float*)(ws + 2445312);   // 1024 f32 (bih0+bhh0)
  float* B1   = (float*)(ws + 2449408);   // 1024 f32
  short* Z    = (short*)(ws + 2453504);   // 1024x384 bf16
  short* EW1T = (short*)(ws + 3239936);   // 64x1536x384 bf16 (75.5 MB)
  short* H0A  = (short*)(ws + 78737408);  // 51200x256 bf16 (26.2 MB)
  float* XG   = (float*)(ws + 104951808); // 51200x1024 f32 (209.7 MB, reused for both layers)

  hipLaunchKernelGGL(prep_cast, dim3(1024), dim3(256), 0, stream, wih0, whh0, wih1, whh1, bih0,
                     bhh0, bih1, bhh1, WIH0, WHH0, WIH1, WHH1, B0, B1);
  hipLaunchKernelGGL(transpose_cast, dim3(8, 16, 1), dim3(256), 0, stream, rW1, RW1T, 256, 512);
  hipLaunchKernelGGL(transpose_cast, dim3(16, 8, 1), dim3(256), 0, stream, rW2, RW2T, 512, 256);
  hipLaunchKernelGGL(transpose_cast, dim3(3, 6, 1), dim3(256), 0, stream, uW1, UW1T, 96, 192);
  hipLaunchKernelGGL(transpose_cast, dim3(6, 4, 1), dim3(256), 0, stream, uW2, UW2T, 192, 128);
  hipLaunchKernelGGL(transpose_cast, dim3(12, 48, 64), dim3(256), 0, stream, eW1, EW1T, 384, 1536);

  hipLaunchKernelGGL(xg_gather_gemm, dim3(400, 4), dim3(512), 0, stream, ratings, remb, WIH0, B0, XG);
  hipLaunchKernelGGL(lstm_rec_store, dim3(64), dim3(512), 0, stream, XG, WHH0, H0A);
  hipLaunchKernelGGL(xg_h_gemm, dim3(400, 4), dim3(512), 0, stream, H0A, WIH1, B1, XG);
  hipLaunchKernelGGL(lstm_rec_tail, dim3(64), dim3(512), 0, stream, XG, WHH1, uids, udata, uemb,
                     RW1T, rb1, RW2T, rb2, UW1T, ub1, UW2T, ub2, Z);
  hipLaunchKernelGGL(expert_mlp, dim3(512), dim3(512), 0, stream, Z, EW1T, eb1, eW2, eb2, out);
}